// Round 27
// baseline (235.494 us; speedup 1.0000x reference)
//
#include <hip/hip_runtime.h>
#include <hip/hip_bf16.h>
#include <float.h>

#define GG    64
#define NPG   1024
#define EPG   8192      // edges per graph
#define NE    524288
#define FIN   128
#define HID   256
#define K1    512
#define K2    256
#define NN0   65536     // GG*NPG
#define NN1   32768     // GG*K1
#define NN2   16384     // GG*K2
#define EPSBN 1e-5f

typedef _Float16 f16x8 __attribute__((ext_vector_type(8)));
typedef _Float16 f16x4 __attribute__((ext_vector_type(4)));
typedef float f32x4 __attribute__((ext_vector_type(4)));

__device__ __forceinline__ float gelu_exact(float v) {
    return 0.5f * v * (1.0f + erff(v * 0.7071067811865476f));
}

// async global->LDS, 16B per lane; lds dest must be wave-uniform base
__device__ __forceinline__ void gld16(const void* g, void* lds) {
    __builtin_amdgcn_global_load_lds(
        (const __attribute__((address_space(1))) unsigned int*)g,
        (__attribute__((address_space(3))) unsigned int*)lds, 16, 0, 0);
}

// ---------- merged prep + CSR ----------
// W stored K-CHUNK-MAJOR: unit (k>>3, n) at [(k>>3)*256 + n]*8 + (k&7).
// GEMM staging is then a pure linear copy and B fragment reads are
// consecutive-lane contiguous (conflict-free b128 pattern).
__global__ __launch_bounds__(512) void k_prepcsr(
        const int* __restrict__ src, const int* __restrict__ dst,
        int* __restrict__ rowp, int* __restrict__ ssrc, int* __restrict__ map1,
        const float* __restrict__ Wrel1, const float* __restrict__ Wroot1,
        const float* __restrict__ Wrel2, const float* __restrict__ Wroot2,
        const float* __restrict__ p2,
        _Float16* __restrict__ W1h, _Float16* __restrict__ W2h,
        float* __restrict__ q2, float* __restrict__ stats1,
        float* __restrict__ stats2) {
    __shared__ int cnt[NPG];
    __shared__ int sa[NPG];
    __shared__ int sb[NPG];
    __shared__ float red[256];
    const int b = blockIdx.x, tid = threadIdx.x;
    if (b < 64) {
        const int g = b;
        const int eb = g * EPG;
        for (int i = g * 512 + tid; i < NN0; i += GG * 512) map1[i] = -1;
        for (int i = tid; i < NPG; i += 512) cnt[i] = 0;
        __syncthreads();
        for (int e = tid; e < EPG; e += 512)
            atomicAdd(&cnt[dst[eb + e] & (NPG - 1)], 1);
        __syncthreads();
        for (int i = tid; i < NPG; i += 512) sa[i] = cnt[i];
        __syncthreads();
        int* cur = sa; int* nxt = sb;
        for (int d = 1; d < NPG; d <<= 1) {             // inclusive scan
            for (int i = tid; i < NPG; i += 512)
                nxt[i] = cur[i] + ((i >= d) ? cur[i - d] : 0);
            __syncthreads();
            int* t = cur; cur = nxt; nxt = t;
        }
        for (int i = tid; i < NPG; i += 512) {
            const int st = cur[i] - cnt[i];             // exclusive start
            rowp[g * (NPG + 1) + i] = st;
            cnt[i] = st;                                // reuse as cursor
        }
        if (tid == 0) rowp[g * (NPG + 1) + NPG] = EPG;
        __syncthreads();
        for (int e = tid; e < EPG; e += 512) {
            const int d = dst[eb + e] & (NPG - 1);
            const int p = atomicAdd(&cnt[d], 1);
            ssrc[eb + p] = src[eb + e] & (NPG - 1);
        }
    } else if (b < 192) {                               // W1: 256n x 256k
        const int i = (b - 64) * 512 + tid;
        const int n = i >> 8, k = i & 255;
        const float v = (k < FIN) ? Wrel1[k * HID + n] : Wroot1[(k - FIN) * HID + n];
        W1h[((k >> 3) << 11) + (n << 3) + (k & 7)] = (_Float16)v;
    } else if (b < 448) {                               // W2: 256n x 512k
        const int i = (b - 192) * 512 + tid;
        const int n = i >> 9, k = i & 511;
        const float v = (k < HID) ? Wrel2[k * HID + n] : Wroot2[(k - HID) * HID + n];
        W2h[((k >> 3) << 11) + (n << 3) + (k & 7)] = (_Float16)v;
    } else if (b == 448) {                              // q2 = p2/||p2||
        if (tid < 256) { const float pv = p2[tid]; red[tid] = pv * pv; }
        __syncthreads();
        for (int s = 128; s > 0; s >>= 1) {
            if (tid < s) red[tid] += red[tid + s];
            __syncthreads();
        }
        if (tid < 256) q2[tid] = p2[tid] * rsqrtf(red[0]);
    } else {                                            // zero BN stats (512 each)
        stats1[tid] = 0.f;
        stats2[tid] = 0.f;
    }
}

// ---------- agg1: CSR gather-sum + own-row copy, fp32 in, fp16 out ----------
__global__ __launch_bounds__(256) void k_agg1(const float* __restrict__ x,
        const int* __restrict__ rowp, const int* __restrict__ ssrc,
        _Float16* __restrict__ A1) {
    const int b = blockIdx.x;
    const int g = b & 63;
    const int ng = b >> 6;                              // 0..127
    const int tid = threadIdx.x;
    const int ln = tid & 31;                            // col float4 0..31
    const int node = (ng << 3) + (tid >> 5);            // 0..1023
    const int s0 = rowp[g * (NPG + 1) + node];
    const int s1 = rowp[g * (NPG + 1) + node + 1];
    const float4* x4 = reinterpret_cast<const float4*>(x);
    const size_t gb = (size_t)(g << 10) * 32;           // 32 float4 per x row
    const int* sp = ssrc + (size_t)g * EPG;
    float4 acc = make_float4(0.f, 0.f, 0.f, 0.f);
    for (int j = s0; j < s1; ++j) {
        const float4 v = x4[gb + (size_t)sp[j] * 32 + ln];
        acc.x += v.x; acc.y += v.y; acc.z += v.z; acc.w += v.w;
    }
    const size_t rb = ((size_t)((g << 10) + node)) * 256;
    *reinterpret_cast<f16x4*>(&A1[rb + (ln << 2)]) =
        (f16x4){(_Float16)acc.x, (_Float16)acc.y, (_Float16)acc.z, (_Float16)acc.w};
    const float4 xv = x4[gb + (size_t)node * 32 + ln];  // lin_root operand
    *reinterpret_cast<f16x4*>(&A1[rb + 128 + (ln << 2)]) =
        (f16x4){(_Float16)xv.x, (_Float16)xv.y, (_Float16)xv.z, (_Float16)xv.w};
}

// ---------- agg2: reuse layer-1 CSR buckets, fp16 in/out ----------
__global__ __launch_bounds__(256) void k_agg2(const _Float16* __restrict__ A2r,
        const int* __restrict__ rowp, const int* __restrict__ ssrc,
        const int* __restrict__ perm1, const int* __restrict__ map1,
        _Float16* __restrict__ A2w) {
    const int b = blockIdx.x;
    const int g = b & 63;
    const int ng = b >> 6;                              // 0..127
    const int tid = threadIdx.x;
    const int ln = tid & 63;                            // col quad 0..63
    const int ni = (ng << 2) + (tid >> 6);              // new node 0..511
    const int on = perm1[(g << 9) + ni] & (NPG - 1);    // old node id
    const int s0 = rowp[g * (NPG + 1) + on];
    const int s1 = rowp[g * (NPG + 1) + on + 1];
    const int* sp = ssrc + (size_t)g * EPG;
    const int* mp = map1 + ((size_t)g << 10);
    float4 acc = make_float4(0.f, 0.f, 0.f, 0.f);
    for (int j = s0; j < s1; ++j) {
        const int ms = mp[sp[j]];                       // global new id or -1
        if (ms < 0) continue;                           // lane-uniform branch
        const f16x4 v = *reinterpret_cast<const f16x4*>(
            &A2r[(size_t)ms * 512 + 256 + (ln << 2)]);
        acc.x += (float)v[0]; acc.y += (float)v[1];
        acc.z += (float)v[2]; acc.w += (float)v[3];
    }
    *reinterpret_cast<f16x4*>(&A2w[((size_t)((g << 9) + ni)) * 512 + (ln << 2)]) =
        (f16x4){(_Float16)acc.x, (_Float16)acc.y, (_Float16)acc.z, (_Float16)acc.w};
}

// ---------- fp16 MFMA GEMM, B-resident-in-LDS, depth-3 A prefetch ----------
// C[M][256] = A[M][K] @ B[256][K]^T. 512 threads, 8 waves, single stage
// barrier per phase. Hot loop: explicit rotating depth-3 A prefetch
// (a0/a1/a2 live + incoming a3, named regs, compile-time indexed) +
// sched_barrier(0) pinning the ks+3 load issue BEFORE the MFMA cluster --
// the consumed fragment was issued THREE iterations (~1300cy ds_read+MFMA)
// earlier, fully covering HBM latency that hipcc's late-issue scheduling
// left exposed (R25: 104-VGPR remat; R26: depth-2 pin gave -7us).
// B k-chunk-major: linear coalesced stage, contiguous conflict-free reads.
// EPI 0: +bias; 1: +bias, gelu, col stats; 2: +bias, fused full score-dot.
template<int K, int EPI, int MCH>
__global__ __launch_bounds__(512, 1) void k_gemmB(
        const _Float16* __restrict__ A, const _Float16* __restrict__ B,
        const float* __restrict__ bias, _Float16* __restrict__ C,
        float* __restrict__ stats, const float* __restrict__ qv2,
        float* __restrict__ scores, int M) {
    __shared__ _Float16 Bs[256 * 256];                   // 128 KB, k-chunk-major
    __shared__ float csum[256];
    __shared__ float csq[256];
    const int tid = threadIdx.x;
    const int l = tid & 63, w = tid >> 6;                // 8 waves
    constexpr int BM = 8 * MCH * 16;
    const int m0 = blockIdx.x * BM;
    const int r16 = l & 15, kg = l >> 4;

    f32x4 acc[MCH][16] = {};
    constexpr int PH = K / 256;

#pragma unroll
    for (int ph = 0; ph < PH; ++ph) {
        if (ph) __syncthreads();                         // prior-phase reads done
        // linear B stage: 8192 16B units (kchunk-major)
        for (int u = tid; u < 8192; u += 512)
            gld16(B + ((size_t)ph * 8192 + u) * 8, (char*)Bs + u * 16);
        asm volatile("s_waitcnt vmcnt(0)" ::: "memory");
        __syncthreads();                                 // B resident

        // rotating depth-3 A prefetch; a0 consumed, a1/a2/a3 in flight
        f16x8 a0[MCH], a1[MCH], a2[MCH];
#pragma unroll
        for (int mc = 0; mc < MCH; ++mc) {
            const int mrow = m0 + (w * MCH + mc) * 16 + r16;
            a0[mc] = *reinterpret_cast<const f16x8*>(
                A + (size_t)mrow * K + ph * 256 + 0 * 32 + kg * 8);
            a1[mc] = *reinterpret_cast<const f16x8*>(
                A + (size_t)mrow * K + ph * 256 + 1 * 32 + kg * 8);
            a2[mc] = *reinterpret_cast<const f16x8*>(
                A + (size_t)mrow * K + ph * 256 + 2 * 32 + kg * 8);
        }
#pragma unroll
        for (int ks = 0; ks < 8; ++ks) {
            f16x8 a3[MCH];
            if (ks + 3 < 8) {
#pragma unroll
                for (int mc = 0; mc < MCH; ++mc) {
                    const int mrow = m0 + (w * MCH + mc) * 16 + r16;
                    a3[mc] = *reinterpret_cast<const f16x8*>(
                        A + (size_t)mrow * K + ph * 256 + (ks + 3) * 32 + kg * 8);
                }
            }
            __builtin_amdgcn_sched_barrier(0);           // pin load issue early
#pragma unroll
            for (int ni = 0; ni < 16; ++ni) {
                const int brow = ni * 16 + r16;          // col index
                const int c = ks * 4 + kg;               // k-chunk
                const f16x8 bf = *reinterpret_cast<const f16x8*>(
                    (const char*)Bs + ((c << 8) + brow) * 16);
#pragma unroll
                for (int mc = 0; mc < MCH; ++mc)
                    acc[mc][ni] = __builtin_amdgcn_mfma_f32_16x16x32_f16(
                        a0[mc], bf, acc[mc][ni], 0, 0, 0);
            }
#pragma unroll
            for (int mc = 0; mc < MCH; ++mc) {
                a0[mc] = a1[mc]; a1[mc] = a2[mc]; a2[mc] = a3[mc];
            }
        }
    }

    if (EPI == 1) {
        __syncthreads();
        if (tid < 256) { csum[tid] = 0.f; csq[tid] = 0.f; }
        __syncthreads();
    }

    float sp[MCH][4];
    if (EPI == 2) {
#pragma unroll
        for (int mc = 0; mc < MCH; ++mc)
#pragma unroll
            for (int r = 0; r < 4; ++r) sp[mc][r] = 0.f;
    }
#pragma unroll
    for (int ni = 0; ni < 16; ++ni) {
        const int col = ni * 16 + r16;
        const float bc = bias[col];
        const float qvn = (EPI == 2) ? qv2[col] : 0.f;
        float sA = 0.f, qA = 0.f;
#pragma unroll
        for (int mc = 0; mc < MCH; ++mc) {
#pragma unroll
            for (int r = 0; r < 4; ++r) {
                const int row = m0 + (w * MCH + mc) * 16 + (kg << 2) + r;
                float t = acc[mc][ni][r] + bc;
                if (EPI == 1) {
                    t = gelu_exact(t);
                    sA += t;
                    qA += t * t;
                }
                if (EPI == 2) sp[mc][r] += t * qvn;
                C[(size_t)row * 256 + col] = (_Float16)t;
            }
        }
        if (EPI == 1) {
            unsafeAtomicAdd(&csum[col], sA);
            unsafeAtomicAdd(&csq[col], qA);
        }
    }
    if (EPI == 1) {
        __syncthreads();
        if (tid < 256) {
            unsafeAtomicAdd(&stats[tid], csum[tid]);
            unsafeAtomicAdd(&stats[HID + tid], csq[tid]);
        }
    }
    if (EPI == 2) {
        // full dot per row completed in-wave; reduce across r16 lanes
#pragma unroll
        for (int mc = 0; mc < MCH; ++mc)
#pragma unroll
            for (int r = 0; r < 4; ++r) {
                float s = sp[mc][r];
                s += __shfl_xor(s, 1);
                s += __shfl_xor(s, 2);
                s += __shfl_xor(s, 4);
                s += __shfl_xor(s, 8);
                if (r16 == 0)
                    scores[m0 + (w * MCH + mc) * 16 + (kg << 2) + r] = s;
            }
    }
}

// ---------- BN finalize / score fold ----------
__global__ __launch_bounds__(256) void k_finalize1(const float* __restrict__ stats,
        const float* __restrict__ g1, const float* __restrict__ bt1,
        const float* __restrict__ p1, float* __restrict__ scale,
        float* __restrict__ shift, float* __restrict__ q, float* __restrict__ r) {
    __shared__ float red[256];
    const int c = threadIdx.x;
    const float m = stats[c] * (1.f / NN0);
    const float v = stats[HID + c] * (1.f / NN0) - m * m;
    const float sc = g1[c] * rsqrtf(v + EPSBN);
    const float sh = bt1[c] - m * sc;
    scale[c] = sc;
    shift[c] = sh;
    const float pv = p1[c];
    red[c] = pv * pv;
    __syncthreads();
    for (int s = 128; s > 0; s >>= 1) {
        if (c < s) red[c] += red[c + s];
        __syncthreads();
    }
    const float inv = rsqrtf(red[0]);
    q[c] = sc * pv * inv;
    __syncthreads();
    red[c] = sh * pv * inv;
    __syncthreads();
    for (int s = 128; s > 0; s >>= 1) {
        if (c < s) red[c] += red[c + s];
        __syncthreads();
    }
    if (c == 0) r[0] = red[0];
}

__global__ __launch_bounds__(256) void k_finalize2(const float* __restrict__ stats,
        const float* __restrict__ g2, const float* __restrict__ bt2,
        float* __restrict__ scale, float* __restrict__ shift) {
    const int c = threadIdx.x;
    const float m = stats[c] * (1.f / NN1);
    const float v = stats[HID + c] * (1.f / NN1) - m * m;
    const float sc = g2[c] * rsqrtf(v + EPSBN);
    scale[c] = sc;
    shift[c] = bt2[c] - m * sc;
}

// ---------- scores (layer1): raw dot h.q + r (tanh applied in topk) ----------
__global__ __launch_bounds__(256) void k_score(const _Float16* __restrict__ H,
        const float* __restrict__ q, const float* __restrict__ r,
        float* __restrict__ out) {
    const int node = blockIdx.x * 4 + (threadIdx.x >> 6);
    const int lane = threadIdx.x & 63;
    const f16x4 h = *reinterpret_cast<const f16x4*>(H + (size_t)node * HID + (lane << 2));
    const float4 qv = *reinterpret_cast<const float4*>(q + (lane << 2));
    float d = (float)h[0] * qv.x + (float)h[1] * qv.y +
              (float)h[2] * qv.z + (float)h[3] * qv.w;
#pragma unroll
    for (int off = 32; off > 0; off >>= 1) d += __shfl_xor(d, off);
    if (lane == 0) out[node] = d + (r ? r[0] : 0.f);
}

// ---------- per-graph bitonic top-k (sums nparts partials, tanh at load) ----
template<int NN_, int KK_, int NT_>
__global__ __launch_bounds__(NT_) void k_topk(const float* __restrict__ scores,
        int nparts, int pstride, int* __restrict__ perm,
        float* __restrict__ vals, int* __restrict__ mapping) {
    __shared__ float s[NN_];
    __shared__ int id[NN_];
    const int g = blockIdx.x, tid = threadIdx.x;
    for (int i = tid; i < NN_; i += NT_) {
        float raw = 0.f;
        for (int p = 0; p < nparts; ++p)
            raw += scores[(size_t)p * pstride + g * NN_ + i];
        s[i] = tanhf(raw);
        id[i] = i;
    }
    __syncthreads();
    for (int k = 2; k <= NN_; k <<= 1) {
        for (int j = k >> 1; j > 0; j >>= 1) {
            for (int t = tid; t < NN_; t += NT_) {
                const int ixj = t ^ j;
                if (ixj > t) {
                    const bool desc = ((t & k) == 0);
                    const float s1 = s[t], s2 = s[ixj];
                    const int i1 = id[t], i2 = id[ixj];
                    const bool inOrder = (s1 > s2) || (s1 == s2 && i1 < i2);
                    if (inOrder != desc) { s[t] = s2; s[ixj] = s1; id[t] = i2; id[ixj] = i1; }
                }
            }
            __syncthreads();
        }
    }
    for (int i = tid; i < KK_; i += NT_) {
        const int oid = id[i];
        perm[g * KK_ + i] = g * NN_ + oid;
        vals[g * KK_ + i] = s[i];
        if (mapping) mapping[g * NN_ + oid] = g * KK_ + i;
    }
}

// ---------- pool1 stage 1: stats/readout partials only ----------
__global__ __launch_bounds__(256) void k_pool1p(const _Float16* __restrict__ HG,
        const int* __restrict__ perm, const float* __restrict__ vals,
        const float* __restrict__ scale1, const float* __restrict__ shift1,
        float* __restrict__ pmax, float* __restrict__ psum,
        float* __restrict__ psq) {
    const int b = blockIdx.x;
    const int g = b >> 3, ig = b & 7;
    const int c = threadIdx.x;
    const float sc = scale1[c], sh = shift1[c];
    float mx = -FLT_MAX, sm = 0.f, sq = 0.f;
    for (int i = ig * 64; i < ig * 64 + 64; ++i) {
        const int idx = (g << 9) + i;
        const int srow = perm[idx];
        const float val = vals[idx];
        const float hv = (float)HG[(size_t)srow * HID + c];
        const float xn = (hv * sc + sh) * val;
        mx = fmaxf(mx, xn);
        sm += xn;
        sq += xn * xn;
    }
    pmax[b * 256 + c] = mx;
    psum[b * 256 + c] = sm;
    psq[b * 256 + c] = sq;
}

// ---------- pool1 stage 2: reduce 8 partials, x1 readout, bn2 stats ----------
__global__ __launch_bounds__(256) void k_pool1r(const float* __restrict__ pmax,
        const float* __restrict__ psum, const float* __restrict__ psq,
        float* __restrict__ X1, float* __restrict__ stats2) {
    const int g = blockIdx.x, c = threadIdx.x;
    float mx = -FLT_MAX, sm = 0.f, sq = 0.f;
    for (int ig = 0; ig < 8; ++ig) {
        const int o = ((g << 3) + ig) * 256 + c;
        mx = fmaxf(mx, pmax[o]);
        sm += psum[o];
        sq += psq[o];
    }
    X1[g * 512 + c] = mx;
    X1[g * 512 + 256 + c] = sm * (1.f / K1);
    unsafeAtomicAdd(&stats2[c], sm);
    unsafeAtomicAdd(&stats2[HID + c], sq);
}

// ---------- h2in: gather HG, BN1*val + BN2 + gelu -> fp16 A2 right half -----
__global__ __launch_bounds__(256) void k_h2in(const _Float16* __restrict__ HG,
        const int* __restrict__ perm, const float* __restrict__ vals,
        const float* __restrict__ scale1, const float* __restrict__ shift1,
        const float* __restrict__ scale2, const float* __restrict__ shift2,
        _Float16* __restrict__ A2) {
    const int i = blockIdx.x * 256 + threadIdx.x;       // NN1*64
    const int idx = i >> 6, c4 = i & 63;
    const int srow = perm[idx];
    const float val = vals[idx];
    const f16x4 h = *reinterpret_cast<const f16x4*>(&HG[(size_t)srow * HID + (c4 << 2)]);
    const float4 s1 = reinterpret_cast<const float4*>(scale1)[c4];
    const float4 b1 = reinterpret_cast<const float4*>(shift1)[c4];
    const float4 s2 = reinterpret_cast<const float4*>(scale2)[c4];
    const float4 b2 = reinterpret_cast<const float4*>(shift2)[c4];
    const float x0 = ((float)h[0] * s1.x + b1.x) * val;
    const float x1 = ((float)h[1] * s1.y + b1.y) * val;
    const float x2 = ((float)h[2] * s1.z + b1.z) * val;
    const float x3 = ((float)h[3] * s1.w + b1.w) * val;
    *reinterpret_cast<f16x4*>(&A2[(size_t)idx * 512 + 256 + (c4 << 2)]) =
        (f16x4){(_Float16)gelu_exact(x0 * s2.x + b2.x),
                (_Float16)gelu_exact(x1 * s2.y + b2.y),
                (_Float16)gelu_exact(x2 * s2.z + b2.z),
                (_Float16)gelu_exact(x3 * s2.w + b2.w)};
}

// ---------- x2 readout, stage 1: 512 blocks (g x 8 row-groups of 32) -------
__global__ __launch_bounds__(256) void k_x2p(const _Float16* __restrict__ H2,
        const int* __restrict__ perm, const float* __restrict__ vals,
        float* __restrict__ pmax, float* __restrict__ psum) {
    const int b = blockIdx.x;
    const int g = b >> 3, ig = b & 7;
    const int c = threadIdx.x;
    float mx = -FLT_MAX, sm = 0.f;
    for (int i = ig * 32; i < ig * 32 + 32; ++i) {
        const int idx = (g << 8) + i;
        const int srow = perm[idx];
        const float v = (float)H2[(size_t)srow * HID + c] * vals[idx];
        mx = fmaxf(mx, v);
        sm += v;
    }
    pmax[b * 256 + c] = mx;
    psum[b * 256 + c] = sm;
}

// ---------- x2 stage 2 + final linear fused ----------
__global__ __launch_bounds__(256) void k_x2final(const float* __restrict__ pmax,
        const float* __restrict__ psum, const float* __restrict__ X1,
        const float* __restrict__ Wl, const float* __restrict__ bl,
        float* __restrict__ out) {
    __shared__ float sx2[512];
    const int g = blockIdx.x, c = threadIdx.x;
    float mx = -FLT_MAX, sm = 0.f;
    for (int ig = 0; ig < 8; ++ig) {
        const int o = ((g << 3) + ig) * 256 + c;
        mx = fmaxf(mx, pmax[o]);
        sm += psum[o];
    }
    sx2[c] = mx;
    sx2[256 + c] = sm * (1.f / K2);
    __syncthreads();
    float acc = bl[c];
    for (int k = 0; k < 512; ++k) {
        const float xv = X1[g * 512 + k] + sx2[k];
        acc = fmaf(xv, Wl[k * HID + c], acc);
    }
    out[g * HID + c] = acc;
}

extern "C" void kernel_launch(void* const* d_in, const int* in_sizes, int n_in,
                              void* d_out, int out_size, void* d_ws, size_t ws_size,
                              hipStream_t stream) {
    (void)in_sizes; (void)n_in; (void)out_size; (void)ws_size;
    const float* x       = (const float*)d_in[0];
    const int*   src     = (const int*)  d_in[1];
    const int*   dst     = (const int*)  d_in[2];
    const float* W_rel1  = (const float*)d_in[3];
    const float* b_rel1  = (const float*)d_in[4];
    const float* W_root1 = (const float*)d_in[5];
    const float* g1      = (const float*)d_in[6];
    const float* bt1     = (const float*)d_in[7];
    const float* p1      = (const float*)d_in[8];
    const float* g2      = (const float*)d_in[9];
    const float* bt2     = (const float*)d_in[10];
    const float* W_rel2  = (const float*)d_in[11];
    const float* b_rel2  = (const float*)d_in[12];
    const float* W_root2 = (const float*)d_in[13];
    const float* p2      = (const float*)d_in[14];
    const float* Wl      = (const float*)d_in[15];
    const float* bl      = (const float*)d_in[16];
    float* out = (float*)d_out;

    char* w = (char*)d_ws;
    size_t off = 0;
    auto alloc = [&](size_t bytes) -> void* {
        void* p = w + off;
        off += (bytes + 255) & ~(size_t)255;
        return p;
    };
    _Float16* A1  = (_Float16*)alloc((size_t)NN0 * 256 * 2);  // 32 MB: [agg|x] fp16
    _Float16* HG  = (_Float16*)alloc((size_t)NN0 * 256 * 2);  // 32 MB: gelu(conv1) fp16
    _Float16* H2  = (_Float16*)alloc((size_t)NN1 * 256 * 2);  // 16 MB: conv2 out fp16
    int*   ROWP   = (int*)  alloc((size_t)GG * (NPG + 1) * 4);
    int*   SSRC   = (int*)  alloc((size_t)NE * 4);
    float* SCORES = (float*)alloc((size_t)NN0 * 4);
    int*   PERM1  = (int*)  alloc((size_t)NN1 * 4);
    float* VALS1  = (float*)alloc((size_t)NN1 * 4);
    int*   MAP1   = (int*)  alloc((size_t)NN0 * 4);
    int*   PERM2  = (int*)  alloc((size_t)NN2 * 4);
    float* VALS2  = (float*)alloc((size_t)NN2 * 4);
    float* STATS1 = (float*)alloc(512 * 4);
    float* STATS2 = (float*)alloc(512 * 4);
    float* SCALE1 = (float*)alloc(256 * 4);
    float* SHIFT1 = (float*)alloc(256 * 4);
    float* Q1     = (float*)alloc(256 * 4);
    float* R1     = (float*)alloc(256);
    float* SCALE2 = (float*)alloc(256 * 4);
    float* SHIFT2 = (float*)alloc(256 * 4);
    float* Q2     = (float*)alloc(256 * 4);
    _Float16* W1h = (_Float16*)alloc((size_t)256 * 256 * 2);
    _Float16* W2h = (_Float16*)alloc((size_t)256 * 512 * 2);
    float* X1     = (float*)alloc((size_t)GG * 512 * 4);
    float* PMAX   = (float*)alloc((size_t)512 * 256 * 4);
    float* PSUM   = (float*)alloc((size_t)512 * 256 * 4);
    float* PSQ    = (float*)alloc((size_t)512 * 256 * 4);
    // alias (stream-ordered): A1 dead after gemm1; A2 must NOT alias HG
    // (h2in/agg2 read HG while writing A2).
    _Float16* A2 = A1;

    k_prepcsr<<<450, 512, 0, stream>>>(src, dst, ROWP, SSRC, MAP1,
        W_rel1, W_root1, W_rel2, W_root2, p2, W1h, W2h, Q2, STATS1, STATS2);
    k_agg1<<<8192, 256, 0, stream>>>(x, ROWP, SSRC, A1);
    k_gemmB<256, 1, 2><<<256, 512, 0, stream>>>(A1, W1h, b_rel1, HG, STATS1,
        nullptr, nullptr, NN0);
    k_finalize1<<<1, 256, 0, stream>>>(STATS1, g1, bt1, p1, SCALE1, SHIFT1, Q1, R1);
    k_score<<<NN0 / 4, 256, 0, stream>>>(HG, Q1, R1, SCORES);
    k_topk<NPG, K1, 1024><<<GG, 1024, 0, stream>>>(SCORES, 1, 0, PERM1, VALS1, MAP1);
    k_pool1p<<<512, 256, 0, stream>>>(HG, PERM1, VALS1, SCALE1, SHIFT1, PMAX, PSUM, PSQ);
    k_pool1r<<<GG, 256, 0, stream>>>(PMAX, PSUM, PSQ, X1, STATS2);
    k_finalize2<<<1, 256, 0, stream>>>(STATS2, g2, bt2, SCALE2, SHIFT2);
    k_h2in<<<8192, 256, 0, stream>>>(HG, PERM1, VALS1, SCALE1, SHIFT1,
        SCALE2, SHIFT2, A2);
    k_agg2<<<8192, 256, 0, stream>>>(A2, ROWP, SSRC, PERM1, MAP1, A2);
    k_gemmB<512, 2, 1><<<256, 512, 0, stream>>>(A2, W2h, b_rel2, H2, nullptr,
        Q2, SCORES, NN1);
    k_topk<K1, K2, 512><<<GG, 512, 0, stream>>>(SCORES, 1, 0, PERM2, VALS2, nullptr);
    k_x2p<<<512, 256, 0, stream>>>(H2, PERM2, VALS2, PMAX, PSUM);
    k_x2final<<<GG, 256, 0, stream>>>(PMAX, PSUM, X1, Wl, bl, out);
}

// Round 28
// 234.429 us; speedup vs baseline: 1.0045x; 1.0045x over previous
//
#include <hip/hip_runtime.h>
#include <hip/hip_bf16.h>
#include <float.h>

#define GG    64
#define NPG   1024
#define EPG   8192      // edges per graph
#define NE    524288
#define FIN   128
#define HID   256
#define K1    512
#define K2    256
#define NN0   65536     // GG*NPG
#define NN1   32768     // GG*K1
#define NN2   16384     // GG*K2
#define EPSBN 1e-5f

typedef _Float16 f16x8 __attribute__((ext_vector_type(8)));
typedef _Float16 f16x4 __attribute__((ext_vector_type(4)));
typedef float f32x4 __attribute__((ext_vector_type(4)));

__device__ __forceinline__ float gelu_exact(float v) {
    return 0.5f * v * (1.0f + erff(v * 0.7071067811865476f));
}

// async global->LDS, 16B per lane; lds dest must be wave-uniform base
__device__ __forceinline__ void gld16(const void* g, void* lds) {
    __builtin_amdgcn_global_load_lds(
        (const __attribute__((address_space(1))) unsigned int*)g,
        (__attribute__((address_space(3))) unsigned int*)lds, 16, 0, 0);
}

// ---------- merged prep + CSR ----------
// W stored K-CHUNK-MAJOR: unit (k>>3, n) at [(k>>3)*256 + n]*8 + (k&7).
// GEMM staging is then a pure linear copy and B fragment reads are
// consecutive-lane contiguous (conflict-free b128 pattern).
__global__ __launch_bounds__(512) void k_prepcsr(
        const int* __restrict__ src, const int* __restrict__ dst,
        int* __restrict__ rowp, int* __restrict__ ssrc, int* __restrict__ map1,
        const float* __restrict__ Wrel1, const float* __restrict__ Wroot1,
        const float* __restrict__ Wrel2, const float* __restrict__ Wroot2,
        const float* __restrict__ p2,
        _Float16* __restrict__ W1h, _Float16* __restrict__ W2h,
        float* __restrict__ q2, float* __restrict__ stats1,
        float* __restrict__ stats2) {
    __shared__ int cnt[NPG];
    __shared__ int sa[NPG];
    __shared__ int sb[NPG];
    __shared__ float red[256];
    const int b = blockIdx.x, tid = threadIdx.x;
    if (b < 64) {
        const int g = b;
        const int eb = g * EPG;
        for (int i = g * 512 + tid; i < NN0; i += GG * 512) map1[i] = -1;
        for (int i = tid; i < NPG; i += 512) cnt[i] = 0;
        __syncthreads();
        for (int e = tid; e < EPG; e += 512)
            atomicAdd(&cnt[dst[eb + e] & (NPG - 1)], 1);
        __syncthreads();
        for (int i = tid; i < NPG; i += 512) sa[i] = cnt[i];
        __syncthreads();
        int* cur = sa; int* nxt = sb;
        for (int d = 1; d < NPG; d <<= 1) {             // inclusive scan
            for (int i = tid; i < NPG; i += 512)
                nxt[i] = cur[i] + ((i >= d) ? cur[i - d] : 0);
            __syncthreads();
            int* t = cur; cur = nxt; nxt = t;
        }
        for (int i = tid; i < NPG; i += 512) {
            const int st = cur[i] - cnt[i];             // exclusive start
            rowp[g * (NPG + 1) + i] = st;
            cnt[i] = st;                                // reuse as cursor
        }
        if (tid == 0) rowp[g * (NPG + 1) + NPG] = EPG;
        __syncthreads();
        for (int e = tid; e < EPG; e += 512) {
            const int d = dst[eb + e] & (NPG - 1);
            const int p = atomicAdd(&cnt[d], 1);
            ssrc[eb + p] = src[eb + e] & (NPG - 1);
        }
    } else if (b < 192) {                               // W1: 256n x 256k
        const int i = (b - 64) * 512 + tid;
        const int n = i >> 8, k = i & 255;
        const float v = (k < FIN) ? Wrel1[k * HID + n] : Wroot1[(k - FIN) * HID + n];
        W1h[((k >> 3) << 11) + (n << 3) + (k & 7)] = (_Float16)v;
    } else if (b < 448) {                               // W2: 256n x 512k
        const int i = (b - 192) * 512 + tid;
        const int n = i >> 9, k = i & 511;
        const float v = (k < HID) ? Wrel2[k * HID + n] : Wroot2[(k - HID) * HID + n];
        W2h[((k >> 3) << 11) + (n << 3) + (k & 7)] = (_Float16)v;
    } else if (b == 448) {                              // q2 = p2/||p2||
        if (tid < 256) { const float pv = p2[tid]; red[tid] = pv * pv; }
        __syncthreads();
        for (int s = 128; s > 0; s >>= 1) {
            if (tid < s) red[tid] += red[tid + s];
            __syncthreads();
        }
        if (tid < 256) q2[tid] = p2[tid] * rsqrtf(red[0]);
    } else {                                            // zero BN stats (512 each)
        stats1[tid] = 0.f;
        stats2[tid] = 0.f;
    }
}

// ---------- agg1: CSR gather-sum + own-row copy, fp32 in, fp16 out ----------
__global__ __launch_bounds__(256) void k_agg1(const float* __restrict__ x,
        const int* __restrict__ rowp, const int* __restrict__ ssrc,
        _Float16* __restrict__ A1) {
    const int b = blockIdx.x;
    const int g = b & 63;
    const int ng = b >> 6;                              // 0..127
    const int tid = threadIdx.x;
    const int ln = tid & 31;                            // col float4 0..31
    const int node = (ng << 3) + (tid >> 5);            // 0..1023
    const int s0 = rowp[g * (NPG + 1) + node];
    const int s1 = rowp[g * (NPG + 1) + node + 1];
    const float4* x4 = reinterpret_cast<const float4*>(x);
    const size_t gb = (size_t)(g << 10) * 32;           // 32 float4 per x row
    const int* sp = ssrc + (size_t)g * EPG;
    float4 acc = make_float4(0.f, 0.f, 0.f, 0.f);
    for (int j = s0; j < s1; ++j) {
        const float4 v = x4[gb + (size_t)sp[j] * 32 + ln];
        acc.x += v.x; acc.y += v.y; acc.z += v.z; acc.w += v.w;
    }
    const size_t rb = ((size_t)((g << 10) + node)) * 256;
    *reinterpret_cast<f16x4*>(&A1[rb + (ln << 2)]) =
        (f16x4){(_Float16)acc.x, (_Float16)acc.y, (_Float16)acc.z, (_Float16)acc.w};
    const float4 xv = x4[gb + (size_t)node * 32 + ln];  // lin_root operand
    *reinterpret_cast<f16x4*>(&A1[rb + 128 + (ln << 2)]) =
        (f16x4){(_Float16)xv.x, (_Float16)xv.y, (_Float16)xv.z, (_Float16)xv.w};
}

// ---------- agg2: reuse layer-1 CSR buckets, fp16 in/out ----------
__global__ __launch_bounds__(256) void k_agg2(const _Float16* __restrict__ A2r,
        const int* __restrict__ rowp, const int* __restrict__ ssrc,
        const int* __restrict__ perm1, const int* __restrict__ map1,
        _Float16* __restrict__ A2w) {
    const int b = blockIdx.x;
    const int g = b & 63;
    const int ng = b >> 6;                              // 0..127
    const int tid = threadIdx.x;
    const int ln = tid & 63;                            // col quad 0..63
    const int ni = (ng << 2) + (tid >> 6);              // new node 0..511
    const int on = perm1[(g << 9) + ni] & (NPG - 1);    // old node id
    const int s0 = rowp[g * (NPG + 1) + on];
    const int s1 = rowp[g * (NPG + 1) + on + 1];
    const int* sp = ssrc + (size_t)g * EPG;
    const int* mp = map1 + ((size_t)g << 10);
    float4 acc = make_float4(0.f, 0.f, 0.f, 0.f);
    for (int j = s0; j < s1; ++j) {
        const int ms = mp[sp[j]];                       // global new id or -1
        if (ms < 0) continue;                           // lane-uniform branch
        const f16x4 v = *reinterpret_cast<const f16x4*>(
            &A2r[(size_t)ms * 512 + 256 + (ln << 2)]);
        acc.x += (float)v[0]; acc.y += (float)v[1];
        acc.z += (float)v[2]; acc.w += (float)v[3];
    }
    *reinterpret_cast<f16x4*>(&A2w[((size_t)((g << 9) + ni)) * 512 + (ln << 2)]) =
        (f16x4){(_Float16)acc.x, (_Float16)acc.y, (_Float16)acc.z, (_Float16)acc.w};
}

// ---------- fp16 MFMA GEMM, B-resident-in-LDS, depth-2 A prefetch ----------
// C[M][256] = A[M][K] @ B[256][K]^T. 512 threads, 8 waves, single stage
// barrier per phase. Hot loop: explicit rotating depth-2 A prefetch
// (a0/a1/a2 named regs, compile-time indexed) + sched_barrier(0) pinning
// the ks+2 load issue BEFORE the MFMA cluster -- the consumed fragment was
// issued two iterations (~800cy ds_read+MFMA) earlier, covering HBM
// latency that the compiler's late-issue scheduling left exposed
// (R21/R25: hoists silently rematerialized at 104 VGPR; R26: -7us win).
// B k-chunk-major: linear coalesced stage, contiguous conflict-free reads.
// EPI 0: +bias; 1: +bias, gelu, col stats; 2: +bias, fused full score-dot.
template<int K, int EPI, int MCH>
__global__ __launch_bounds__(512, 1) void k_gemmB(
        const _Float16* __restrict__ A, const _Float16* __restrict__ B,
        const float* __restrict__ bias, _Float16* __restrict__ C,
        float* __restrict__ stats, const float* __restrict__ qv2,
        float* __restrict__ scores, int M) {
    __shared__ _Float16 Bs[256 * 256];                   // 128 KB, k-chunk-major
    __shared__ float csum[256];
    __shared__ float csq[256];
    const int tid = threadIdx.x;
    const int l = tid & 63, w = tid >> 6;                // 8 waves
    constexpr int BM = 8 * MCH * 16;
    const int m0 = blockIdx.x * BM;
    const int r16 = l & 15, kg = l >> 4;

    f32x4 acc[MCH][16] = {};
    constexpr int PH = K / 256;

#pragma unroll
    for (int ph = 0; ph < PH; ++ph) {
        if (ph) __syncthreads();                         // prior-phase reads done
        // linear B stage: 8192 16B units (kchunk-major)
        for (int u = tid; u < 8192; u += 512)
            gld16(B + ((size_t)ph * 8192 + u) * 8, (char*)Bs + u * 16);
        asm volatile("s_waitcnt vmcnt(0)" ::: "memory");
        __syncthreads();                                 // B resident

        // rotating depth-2 A prefetch; a0 consumed, a1/a2 in flight
        f16x8 a0[MCH], a1[MCH];
#pragma unroll
        for (int mc = 0; mc < MCH; ++mc) {
            const int mrow = m0 + (w * MCH + mc) * 16 + r16;
            a0[mc] = *reinterpret_cast<const f16x8*>(
                A + (size_t)mrow * K + ph * 256 + 0 * 32 + kg * 8);
            a1[mc] = *reinterpret_cast<const f16x8*>(
                A + (size_t)mrow * K + ph * 256 + 1 * 32 + kg * 8);
        }
#pragma unroll
        for (int ks = 0; ks < 8; ++ks) {
            f16x8 a2[MCH];
            if (ks + 2 < 8) {
#pragma unroll
                for (int mc = 0; mc < MCH; ++mc) {
                    const int mrow = m0 + (w * MCH + mc) * 16 + r16;
                    a2[mc] = *reinterpret_cast<const f16x8*>(
                        A + (size_t)mrow * K + ph * 256 + (ks + 2) * 32 + kg * 8);
                }
            }
            __builtin_amdgcn_sched_barrier(0);           // pin load issue early
#pragma unroll
            for (int ni = 0; ni < 16; ++ni) {
                const int brow = ni * 16 + r16;          // col index
                const int c = ks * 4 + kg;               // k-chunk
                const f16x8 bf = *reinterpret_cast<const f16x8*>(
                    (const char*)Bs + ((c << 8) + brow) * 16);
#pragma unroll
                for (int mc = 0; mc < MCH; ++mc)
                    acc[mc][ni] = __builtin_amdgcn_mfma_f32_16x16x32_f16(
                        a0[mc], bf, acc[mc][ni], 0, 0, 0);
            }
#pragma unroll
            for (int mc = 0; mc < MCH; ++mc) { a0[mc] = a1[mc]; a1[mc] = a2[mc]; }
        }
    }

    if (EPI == 1) {
        __syncthreads();
        if (tid < 256) { csum[tid] = 0.f; csq[tid] = 0.f; }
        __syncthreads();
    }

    float sp[MCH][4];
    if (EPI == 2) {
#pragma unroll
        for (int mc = 0; mc < MCH; ++mc)
#pragma unroll
            for (int r = 0; r < 4; ++r) sp[mc][r] = 0.f;
    }
#pragma unroll
    for (int ni = 0; ni < 16; ++ni) {
        const int col = ni * 16 + r16;
        const float bc = bias[col];
        const float qvn = (EPI == 2) ? qv2[col] : 0.f;
        float sA = 0.f, qA = 0.f;
#pragma unroll
        for (int mc = 0; mc < MCH; ++mc) {
#pragma unroll
            for (int r = 0; r < 4; ++r) {
                const int row = m0 + (w * MCH + mc) * 16 + (kg << 2) + r;
                float t = acc[mc][ni][r] + bc;
                if (EPI == 1) {
                    t = gelu_exact(t);
                    sA += t;
                    qA += t * t;
                }
                if (EPI == 2) sp[mc][r] += t * qvn;
                C[(size_t)row * 256 + col] = (_Float16)t;
            }
        }
        if (EPI == 1) {
            unsafeAtomicAdd(&csum[col], sA);
            unsafeAtomicAdd(&csq[col], qA);
        }
    }
    if (EPI == 1) {
        __syncthreads();
        if (tid < 256) {
            unsafeAtomicAdd(&stats[tid], csum[tid]);
            unsafeAtomicAdd(&stats[HID + tid], csq[tid]);
        }
    }
    if (EPI == 2) {
        // full dot per row completed in-wave; reduce across r16 lanes
#pragma unroll
        for (int mc = 0; mc < MCH; ++mc)
#pragma unroll
            for (int r = 0; r < 4; ++r) {
                float s = sp[mc][r];
                s += __shfl_xor(s, 1);
                s += __shfl_xor(s, 2);
                s += __shfl_xor(s, 4);
                s += __shfl_xor(s, 8);
                if (r16 == 0)
                    scores[m0 + (w * MCH + mc) * 16 + (kg << 2) + r] = s;
            }
    }
}

// ---------- BN finalize / score fold ----------
__global__ __launch_bounds__(256) void k_finalize1(const float* __restrict__ stats,
        const float* __restrict__ g1, const float* __restrict__ bt1,
        const float* __restrict__ p1, float* __restrict__ scale,
        float* __restrict__ shift, float* __restrict__ q, float* __restrict__ r) {
    __shared__ float red[256];
    const int c = threadIdx.x;
    const float m = stats[c] * (1.f / NN0);
    const float v = stats[HID + c] * (1.f / NN0) - m * m;
    const float sc = g1[c] * rsqrtf(v + EPSBN);
    const float sh = bt1[c] - m * sc;
    scale[c] = sc;
    shift[c] = sh;
    const float pv = p1[c];
    red[c] = pv * pv;
    __syncthreads();
    for (int s = 128; s > 0; s >>= 1) {
        if (c < s) red[c] += red[c + s];
        __syncthreads();
    }
    const float inv = rsqrtf(red[0]);
    q[c] = sc * pv * inv;
    __syncthreads();
    red[c] = sh * pv * inv;
    __syncthreads();
    for (int s = 128; s > 0; s >>= 1) {
        if (c < s) red[c] += red[c + s];
        __syncthreads();
    }
    if (c == 0) r[0] = red[0];
}

__global__ __launch_bounds__(256) void k_finalize2(const float* __restrict__ stats,
        const float* __restrict__ g2, const float* __restrict__ bt2,
        float* __restrict__ scale, float* __restrict__ shift) {
    const int c = threadIdx.x;
    const float m = stats[c] * (1.f / NN1);
    const float v = stats[HID + c] * (1.f / NN1) - m * m;
    const float sc = g2[c] * rsqrtf(v + EPSBN);
    scale[c] = sc;
    shift[c] = bt2[c] - m * sc;
}

// ---------- scores (layer1): raw dot h.q + r (tanh applied in topk) ----------
__global__ __launch_bounds__(256) void k_score(const _Float16* __restrict__ H,
        const float* __restrict__ q, const float* __restrict__ r,
        float* __restrict__ out) {
    const int node = blockIdx.x * 4 + (threadIdx.x >> 6);
    const int lane = threadIdx.x & 63;
    const f16x4 h = *reinterpret_cast<const f16x4*>(H + (size_t)node * HID + (lane << 2));
    const float4 qv = *reinterpret_cast<const float4*>(q + (lane << 2));
    float d = (float)h[0] * qv.x + (float)h[1] * qv.y +
              (float)h[2] * qv.z + (float)h[3] * qv.w;
#pragma unroll
    for (int off = 32; off > 0; off >>= 1) d += __shfl_xor(d, off);
    if (lane == 0) out[node] = d + (r ? r[0] : 0.f);
}

// ---------- per-graph bitonic top-k (sums nparts partials, tanh at load) ----
template<int NN_, int KK_, int NT_>
__global__ __launch_bounds__(NT_) void k_topk(const float* __restrict__ scores,
        int nparts, int pstride, int* __restrict__ perm,
        float* __restrict__ vals, int* __restrict__ mapping) {
    __shared__ float s[NN_];
    __shared__ int id[NN_];
    const int g = blockIdx.x, tid = threadIdx.x;
    for (int i = tid; i < NN_; i += NT_) {
        float raw = 0.f;
        for (int p = 0; p < nparts; ++p)
            raw += scores[(size_t)p * pstride + g * NN_ + i];
        s[i] = tanhf(raw);
        id[i] = i;
    }
    __syncthreads();
    for (int k = 2; k <= NN_; k <<= 1) {
        for (int j = k >> 1; j > 0; j >>= 1) {
            for (int t = tid; t < NN_; t += NT_) {
                const int ixj = t ^ j;
                if (ixj > t) {
                    const bool desc = ((t & k) == 0);
                    const float s1 = s[t], s2 = s[ixj];
                    const int i1 = id[t], i2 = id[ixj];
                    const bool inOrder = (s1 > s2) || (s1 == s2 && i1 < i2);
                    if (inOrder != desc) { s[t] = s2; s[ixj] = s1; id[t] = i2; id[ixj] = i1; }
                }
            }
            __syncthreads();
        }
    }
    for (int i = tid; i < KK_; i += NT_) {
        const int oid = id[i];
        perm[g * KK_ + i] = g * NN_ + oid;
        vals[g * KK_ + i] = s[i];
        if (mapping) mapping[g * NN_ + oid] = g * KK_ + i;
    }
}

// ---------- pool1 stage 1: stats/readout partials only ----------
__global__ __launch_bounds__(256) void k_pool1p(const _Float16* __restrict__ HG,
        const int* __restrict__ perm, const float* __restrict__ vals,
        const float* __restrict__ scale1, const float* __restrict__ shift1,
        float* __restrict__ pmax, float* __restrict__ psum,
        float* __restrict__ psq) {
    const int b = blockIdx.x;
    const int g = b >> 3, ig = b & 7;
    const int c = threadIdx.x;
    const float sc = scale1[c], sh = shift1[c];
    float mx = -FLT_MAX, sm = 0.f, sq = 0.f;
    for (int i = ig * 64; i < ig * 64 + 64; ++i) {
        const int idx = (g << 9) + i;
        const int srow = perm[idx];
        const float val = vals[idx];
        const float hv = (float)HG[(size_t)srow * HID + c];
        const float xn = (hv * sc + sh) * val;
        mx = fmaxf(mx, xn);
        sm += xn;
        sq += xn * xn;
    }
    pmax[b * 256 + c] = mx;
    psum[b * 256 + c] = sm;
    psq[b * 256 + c] = sq;
}

// ---------- pool1 stage 2: reduce 8 partials, x1 readout, bn2 stats ----------
__global__ __launch_bounds__(256) void k_pool1r(const float* __restrict__ pmax,
        const float* __restrict__ psum, const float* __restrict__ psq,
        float* __restrict__ X1, float* __restrict__ stats2) {
    const int g = blockIdx.x, c = threadIdx.x;
    float mx = -FLT_MAX, sm = 0.f, sq = 0.f;
    for (int ig = 0; ig < 8; ++ig) {
        const int o = ((g << 3) + ig) * 256 + c;
        mx = fmaxf(mx, pmax[o]);
        sm += psum[o];
        sq += psq[o];
    }
    X1[g * 512 + c] = mx;
    X1[g * 512 + 256 + c] = sm * (1.f / K1);
    unsafeAtomicAdd(&stats2[c], sm);
    unsafeAtomicAdd(&stats2[HID + c], sq);
}

// ---------- h2in: gather HG, BN1*val + BN2 + gelu -> fp16 A2 right half -----
__global__ __launch_bounds__(256) void k_h2in(const _Float16* __restrict__ HG,
        const int* __restrict__ perm, const float* __restrict__ vals,
        const float* __restrict__ scale1, const float* __restrict__ shift1,
        const float* __restrict__ scale2, const float* __restrict__ shift2,
        _Float16* __restrict__ A2) {
    const int i = blockIdx.x * 256 + threadIdx.x;       // NN1*64
    const int idx = i >> 6, c4 = i & 63;
    const int srow = perm[idx];
    const float val = vals[idx];
    const f16x4 h = *reinterpret_cast<const f16x4*>(&HG[(size_t)srow * HID + (c4 << 2)]);
    const float4 s1 = reinterpret_cast<const float4*>(scale1)[c4];
    const float4 b1 = reinterpret_cast<const float4*>(shift1)[c4];
    const float4 s2 = reinterpret_cast<const float4*>(scale2)[c4];
    const float4 b2 = reinterpret_cast<const float4*>(shift2)[c4];
    const float x0 = ((float)h[0] * s1.x + b1.x) * val;
    const float x1 = ((float)h[1] * s1.y + b1.y) * val;
    const float x2 = ((float)h[2] * s1.z + b1.z) * val;
    const float x3 = ((float)h[3] * s1.w + b1.w) * val;
    *reinterpret_cast<f16x4*>(&A2[(size_t)idx * 512 + 256 + (c4 << 2)]) =
        (f16x4){(_Float16)gelu_exact(x0 * s2.x + b2.x),
                (_Float16)gelu_exact(x1 * s2.y + b2.y),
                (_Float16)gelu_exact(x2 * s2.z + b2.z),
                (_Float16)gelu_exact(x3 * s2.w + b2.w)};
}

// ---------- x2 readout, stage 1: 512 blocks (g x 8 row-groups of 32) -------
__global__ __launch_bounds__(256) void k_x2p(const _Float16* __restrict__ H2,
        const int* __restrict__ perm, const float* __restrict__ vals,
        float* __restrict__ pmax, float* __restrict__ psum) {
    const int b = blockIdx.x;
    const int g = b >> 3, ig = b & 7;
    const int c = threadIdx.x;
    float mx = -FLT_MAX, sm = 0.f;
    for (int i = ig * 32; i < ig * 32 + 32; ++i) {
        const int idx = (g << 8) + i;
        const int srow = perm[idx];
        const float v = (float)H2[(size_t)srow * HID + c] * vals[idx];
        mx = fmaxf(mx, v);
        sm += v;
    }
    pmax[b * 256 + c] = mx;
    psum[b * 256 + c] = sm;
}

// ---------- x2 stage 2 + final linear fused ----------
__global__ __launch_bounds__(256) void k_x2final(const float* __restrict__ pmax,
        const float* __restrict__ psum, const float* __restrict__ X1,
        const float* __restrict__ Wl, const float* __restrict__ bl,
        float* __restrict__ out) {
    __shared__ float sx2[512];
    const int g = blockIdx.x, c = threadIdx.x;
    float mx = -FLT_MAX, sm = 0.f;
    for (int ig = 0; ig < 8; ++ig) {
        const int o = ((g << 3) + ig) * 256 + c;
        mx = fmaxf(mx, pmax[o]);
        sm += psum[o];
    }
    sx2[c] = mx;
    sx2[256 + c] = sm * (1.f / K2);
    __syncthreads();
    float acc = bl[c];
    for (int k = 0; k < 512; ++k) {
        const float xv = X1[g * 512 + k] + sx2[k];
        acc = fmaf(xv, Wl[k * HID + c], acc);
    }
    out[g * HID + c] = acc;
}

extern "C" void kernel_launch(void* const* d_in, const int* in_sizes, int n_in,
                              void* d_out, int out_size, void* d_ws, size_t ws_size,
                              hipStream_t stream) {
    (void)in_sizes; (void)n_in; (void)out_size; (void)ws_size;
    const float* x       = (const float*)d_in[0];
    const int*   src     = (const int*)  d_in[1];
    const int*   dst     = (const int*)  d_in[2];
    const float* W_rel1  = (const float*)d_in[3];
    const float* b_rel1  = (const float*)d_in[4];
    const float* W_root1 = (const float*)d_in[5];
    const float* g1      = (const float*)d_in[6];
    const float* bt1     = (const float*)d_in[7];
    const float* p1      = (const float*)d_in[8];
    const float* g2      = (const float*)d_in[9];
    const float* bt2     = (const float*)d_in[10];
    const float* W_rel2  = (const float*)d_in[11];
    const float* b_rel2  = (const float*)d_in[12];
    const float* W_root2 = (const float*)d_in[13];
    const float* p2      = (const float*)d_in[14];
    const float* Wl      = (const float*)d_in[15];
    const float* bl      = (const float*)d_in[16];
    float* out = (float*)d_out;

    char* w = (char*)d_ws;
    size_t off = 0;
    auto alloc = [&](size_t bytes) -> void* {
        void* p = w + off;
        off += (bytes + 255) & ~(size_t)255;
        return p;
    };
    _Float16* A1  = (_Float16*)alloc((size_t)NN0 * 256 * 2);  // 32 MB: [agg|x] fp16
    _Float16* HG  = (_Float16*)alloc((size_t)NN0 * 256 * 2);  // 32 MB: gelu(conv1) fp16
    _Float16* H2  = (_Float16*)alloc((size_t)NN1 * 256 * 2);  // 16 MB: conv2 out fp16
    int*   ROWP   = (int*)  alloc((size_t)GG * (NPG + 1) * 4);
    int*   SSRC   = (int*)  alloc((size_t)NE * 4);
    float* SCORES = (float*)alloc((size_t)NN0 * 4);
    int*   PERM1  = (int*)  alloc((size_t)NN1 * 4);
    float* VALS1  = (float*)alloc((size_t)NN1 * 4);
    int*   MAP1   = (int*)  alloc((size_t)NN0 * 4);
    int*   PERM2  = (int*)  alloc((size_t)NN2 * 4);
    float* VALS2  = (float*)alloc((size_t)NN2 * 4);
    float* STATS1 = (float*)alloc(512 * 4);
    float* STATS2 = (float*)alloc(512 * 4);
    float* SCALE1 = (float*)alloc(256 * 4);
    float* SHIFT1 = (float*)alloc(256 * 4);
    float* Q1     = (float*)alloc(256 * 4);
    float* R1     = (float*)alloc(256);
    float* SCALE2 = (float*)alloc(256 * 4);
    float* SHIFT2 = (float*)alloc(256 * 4);
    float* Q2     = (float*)alloc(256 * 4);
    _Float16* W1h = (_Float16*)alloc((size_t)256 * 256 * 2);
    _Float16* W2h = (_Float16*)alloc((size_t)256 * 512 * 2);
    float* X1     = (float*)alloc((size_t)GG * 512 * 4);
    float* PMAX   = (float*)alloc((size_t)512 * 256 * 4);
    float* PSUM   = (float*)alloc((size_t)512 * 256 * 4);
    float* PSQ    = (float*)alloc((size_t)512 * 256 * 4);
    // alias (stream-ordered): A1 dead after gemm1; A2 must NOT alias HG
    // (h2in/agg2 read HG while writing A2).
    _Float16* A2 = A1;

    k_prepcsr<<<450, 512, 0, stream>>>(src, dst, ROWP, SSRC, MAP1,
        W_rel1, W_root1, W_rel2, W_root2, p2, W1h, W2h, Q2, STATS1, STATS2);
    k_agg1<<<8192, 256, 0, stream>>>(x, ROWP, SSRC, A1);
    k_gemmB<256, 1, 2><<<256, 512, 0, stream>>>(A1, W1h, b_rel1, HG, STATS1,
        nullptr, nullptr, NN0);
    k_finalize1<<<1, 256, 0, stream>>>(STATS1, g1, bt1, p1, SCALE1, SHIFT1, Q1, R1);
    k_score<<<NN0 / 4, 256, 0, stream>>>(HG, Q1, R1, SCORES);
    k_topk<NPG, K1, 1024><<<GG, 1024, 0, stream>>>(SCORES, 1, 0, PERM1, VALS1, MAP1);
    k_pool1p<<<512, 256, 0, stream>>>(HG, PERM1, VALS1, SCALE1, SHIFT1, PMAX, PSUM, PSQ);
    k_pool1r<<<GG, 256, 0, stream>>>(PMAX, PSUM, PSQ, X1, STATS2);
    k_finalize2<<<1, 256, 0, stream>>>(STATS2, g2, bt2, SCALE2, SHIFT2);
    k_h2in<<<8192, 256, 0, stream>>>(HG, PERM1, VALS1, SCALE1, SHIFT1,
        SCALE2, SHIFT2, A2);
    k_agg2<<<8192, 256, 0, stream>>>(A2, ROWP, SSRC, PERM1, MAP1, A2);
    k_gemmB<512, 2, 1><<<256, 512, 0, stream>>>(A2, W2h, b_rel2, H2, nullptr,
        Q2, SCORES, NN1);
    k_topk<K1, K2, 512><<<GG, 512, 0, stream>>>(SCORES, 1, 0, PERM2, VALS2, nullptr);
    k_x2p<<<512, 256, 0, stream>>>(H2, PERM2, VALS2, PMAX, PSUM);
    k_x2final<<<GG, 256, 0, stream>>>(PMAX, PSUM, X1, Wl, bl, out);
}